// Round 8
// baseline (303.966 us; speedup 1.0000x reference)
//
#include <hip/hip_runtime.h>
#include <hip/hip_bf16.h>

// VectorQuantizer on MI355X — R8: barrier-free scan, global bf16 codebook.
// Inputs (fp32): z[NT,64], codebook[K,64], cluster_size[K], ema_w[K,64]
// d_out (fp32): quantized[NT*64] | indices[NT] | loss[1] | new_codebook[K*64] |
//   new_cluster_size[K] | new_ema_w[K*64]

#define DECAY 0.99f
#define OMD   0.01f
#define EPSV  1e-5f
#define BIASF 192.0f    // score' = 192 + z.c - |c|^2/2  (positive => uint-monotone bits)

typedef __attribute__((ext_vector_type(8))) __bf16 bf16x8;
typedef __attribute__((ext_vector_type(4))) float  float4v;

static __device__ __forceinline__ unsigned short bfbits(float f) {
    __bf16 h = (__bf16)f;
    return __builtin_bit_cast(unsigned short, h);
}
static __device__ __forceinline__ bf16x8 cvt8(float4v a, float4v b) {
    bf16x8 r;
    r[0] = (__bf16)a[0]; r[1] = (__bf16)a[1]; r[2] = (__bf16)a[2]; r[3] = (__bf16)a[3];
    r[4] = (__bf16)b[0]; r[5] = (__bf16)b[1]; r[6] = (__bf16)b[2]; r[7] = (__bf16)b[3];
    return r;
}

// Exact squared distance in fp64 (inputs bf16-valued -> exact).
static __device__ double refine_d2(const float* __restrict__ zr,
                                   const float* __restrict__ cb, int idx, int K) {
    if (idx >= K) return 1.0e300;
    const float* cr = cb + (size_t)idx * 64;
    double s = 0.0;
    #pragma unroll 4
    for (int i = 0; i < 16; ++i) {
        float4v zv = *(const float4v*)(zr + i * 4);
        float4v cv = *(const float4v*)(cr + i * 4);
        #pragma unroll
        for (int j = 0; j < 4; ++j) {
            double e = (double)zv[j] - (double)cv[j];
            s = fma(e, e, s);
        }
    }
    return s;
}

__global__ void vq_prep(const float* __restrict__ cb,
                        unsigned short* __restrict__ cbb,
                        float* __restrict__ cnormp,
                        float* __restrict__ dwacc,
                        int* __restrict__ cnt,
                        float* __restrict__ misc,
                        int K, int Kpad) {
    const int KD = K * 64;
    const int KpadD = Kpad * 64;
    int t = blockIdx.x * 256 + threadIdx.x;      // grid covers Kpad*64
    if (t < KD) { dwacc[t] = 0.f; cbb[t] = bfbits(cb[t]); }
    else if (t < KpadD) cbb[t] = 0;
    if (t < Kpad) {
        cnt[t] = 0;
        if (t < K) {
            const float4v* cp = (const float4v*)(cb + (size_t)t * 64);
            float s = 0.f;
            #pragma unroll
            for (int i = 0; i < 16; ++i) {
                float4v v = cp[i];
                s += v[0] * v[0] + v[1] * v[1] + v[2] * v[2] + v[3] * v[3];
            }
            cnormp[t] = BIASF - 0.5f * s;
        } else cnormp[t] = 0.f;                  // pad -> score 0, never wins
    }
    if (t == 0) misc[0] = 0.f;                   // loss
}

// 256 threads = 4 waves; 128 tokens/block (32/wave). No LDS staging, no
// barriers in the scan: A-fragments stream from L2-resident bf16 codebook.
__launch_bounds__(256)
__global__ void vq_main(const float* __restrict__ z,
                        const float* __restrict__ cb,
                        const unsigned short* __restrict__ cbb,
                        const float* __restrict__ cnormp,
                        int* __restrict__ cnt,
                        float* __restrict__ misc,
                        float* __restrict__ out,
                        int NT, int K, int Ktiles,
                        unsigned kmask, int smallK) {
    __shared__ int hist[1024];

    const int tid  = threadIdx.x;
    const int lane = tid & 63;
    const int wave = tid >> 6;                  // 0..3
    const int col  = lane & 15;
    const int quad = lane >> 4;
    const int wtok0 = blockIdx.x * 128 + wave * 32;

    if (smallK) for (int i = tid; i < K; i += 256) hist[i] = 0;
    __syncthreads();

    // ---- B fragments: this wave's 32 tokens (2 groups of 16) ----
    bf16x8 bf0[2], bf1[2];
    #pragma unroll
    for (int g = 0; g < 2; ++g) {
        int tok = wtok0 + g * 16 + col;
        if (tok >= NT) tok = NT - 1;
        const float* zp = z + (size_t)tok * 64 + quad * 8;
        float4v f0 = *(const float4v*)(zp);
        float4v f1 = *(const float4v*)(zp + 4);
        float4v f2 = *(const float4v*)(zp + 32);
        float4v f3 = *(const float4v*)(zp + 36);
        bf0[g] = cvt8(f0, f1);
        bf1[g] = cvt8(f2, f3);
    }

    // per-lane top-2 packed keys (score bits | candidate#) per token-group
    unsigned k1[2] = { 0u, 0u }, k2[2] = { 0u, 0u };

    #pragma unroll 4
    for (int tt = 0; tt < Ktiles; ++tt) {
        const unsigned short* arow = cbb + (size_t)(tt * 16 + col) * 64;
        bf16x8 a0 = *(const bf16x8*)(arow + quad * 8);
        bf16x8 a1 = *(const bf16x8*)(arow + 32 + quad * 8);
        float4v cni = *(const float4v*)(cnormp + tt * 16 + quad * 4);
        const unsigned iterbase = (unsigned)(tt << 2);
        #pragma unroll
        for (int g = 0; g < 2; ++g) {
            float4v acc = cni;                  // = BIAS - |c|^2/2
            acc = __builtin_amdgcn_mfma_f32_16x16x32_bf16(a0, bf0[g], acc, 0, 0, 0);
            acc = __builtin_amdgcn_mfma_f32_16x16x32_bf16(a1, bf1[g], acc, 0, 0, 0);
            #pragma unroll
            for (int r = 0; r < 4; ++r) {
                unsigned kb = (__float_as_uint(acc[r]) & kmask) | (iterbase + r);
                unsigned lo = k2[g] > kb ? k2[g] : kb;       // max(k2,kb)
                k2[g] = k1[g] < lo ? k1[g] : lo;             // med3
                k1[g] = k1[g] > kb ? k1[g] : kb;             // max
            }
        }
    }

    // ---- fp64 exact refinement over per-lane top-2, cross-quad combine ----
    const unsigned imask = ~kmask;
    int ibst[2];
    #pragma unroll
    for (int g = 0; g < 2; ++g) {
        int tok = wtok0 + g * 16 + col;
        if (tok >= NT) tok = NT - 1;
        const float* zr = z + (size_t)tok * 64;
        unsigned it1 = k1[g] & imask, it2 = k2[g] & imask;
        int ia  = (int)(it1 >> 2) * 16 + quad * 4 + (int)(it1 & 3);
        int ib2 = (int)(it2 >> 2) * 16 + quad * 4 + (int)(it2 & 3);
        double s1 = refine_d2(zr, cb, ia, K);
        double s2 = refine_d2(zr, cb, ib2, K);
        double bs; int bi;
        if (s1 < s2 || (s1 == s2 && ia < ib2)) { bs = s1; bi = ia; }
        else                                    { bs = s2; bi = ib2; }
        #pragma unroll
        for (int off = 16; off <= 32; off <<= 1) {
            double os = __shfl_xor(bs, off, 64);
            int    oi = __shfl_xor(bi, off, 64);
            if (os < bs || (os == bs && oi < bi)) { bs = os; bi = oi; }
        }
        ibst[g] = bi;
    }

    const size_t off_idx = (size_t)NT * 64;

    // ---- indices + histogram ----
    if (lane < 32) {
        int tk = wtok0 + lane;
        if (tk < NT) {
            int ib = (lane < 16) ? ibst[0] : ibst[1];
            out[off_idx + tk] = (float)ib;
            if (smallK) atomicAdd(&hist[ib], 1);
            else        atomicAdd(&cnt[ib], 1);
        }
    }

    // ---- quantized gather + loss ----
    float lsum = 0.f;
    #pragma unroll
    for (int i = 0; i < 8; ++i) {
        int tw  = i * 4 + quad;
        int g   = i >> 2;
        int idx = __shfl(ibst[g], tw & 15, 64);
        int token = wtok0 + tw;
        if (token < NT) {
            int d4 = col * 4;
            float4v zf = *(const float4v*)(z  + (size_t)token * 64 + d4);
            float4v qf = *(const float4v*)(cb + (size_t)idx   * 64 + d4);
            *(float4v*)(out + (size_t)token * 64 + d4) = qf;
            float e0 = zf[0] - qf[0], e1 = zf[1] - qf[1];
            float e2 = zf[2] - qf[2], e3 = zf[3] - qf[3];
            lsum += e0 * e0 + e1 * e1 + e2 * e2 + e3 * e3;
        }
    }
    #pragma unroll
    for (int off = 1; off < 64; off <<= 1) lsum += __shfl_xor(lsum, off, 64);
    if (lane == 0) atomicAdd(misc, lsum);

    __syncthreads();
    if (smallK) {
        for (int k = tid; k < K; k += 256) {
            int c = hist[k];
            if (c) atomicAdd(&cnt[k], c);
        }
    }
}

// Single block: exclusive prefix of cnt -> off/cur, n, loss output.
__global__ void vq_scan(const float* __restrict__ cs,
                        const int* __restrict__ cnt,
                        int* __restrict__ cur, int* __restrict__ off,
                        float* __restrict__ misc,
                        float* __restrict__ out, int NT, int K) {
    __shared__ int sc[1024];
    __shared__ float red[16];
    const int tid = threadIdx.x;

    int carry = 0;
    float cs_part = 0.f;
    int   cnt_part = 0;
    for (int base = 0; base < K; base += 1024) {
        int k = base + tid;
        int c = (k < K) ? cnt[k] : 0;
        if (k < K) { cs_part += cs[k]; cnt_part += c; }
        sc[tid] = c;
        __syncthreads();
        for (int s = 1; s < 1024; s <<= 1) {
            int v = (tid >= s) ? sc[tid - s] : 0;
            __syncthreads();
            sc[tid] += v;
            __syncthreads();
        }
        int incl = sc[tid];
        int excl = incl - c + carry;
        if (k < K) { off[k] = excl; cur[k] = excl; }
        carry += sc[1023];
        __syncthreads();
    }

    float part = DECAY * cs_part + OMD * (float)cnt_part;
    #pragma unroll
    for (int o = 1; o < 64; o <<= 1) part += __shfl_xor(part, o, 64);
    if ((tid & 63) == 0) red[tid >> 6] = part;
    __syncthreads();
    if (tid == 0) {
        float nn = 0.f;
        #pragma unroll
        for (int i = 0; i < 16; ++i) nn += red[i];
        misc[1] = nn;                                        // n
        out[(size_t)NT * 64 + NT] = misc[0] / ((float)NT * 64.0f);  // loss
    }
}

__global__ void vq_scatter(const float* __restrict__ out_idx,
                           int* __restrict__ cur, int* __restrict__ sorted,
                           int NT, int packOK) {
    int t = blockIdx.x * 256 + threadIdx.x;
    if (t < NT) {
        int idx = (int)out_idx[t];
        int pos = atomicAdd(&cur[idx], 1);
        sorted[pos] = packOK ? (t | (idx << 18)) : t;
    }
}

// Balanced segmented reduction: one wave per 64 consecutive sorted tokens.
__launch_bounds__(256)
__global__ void vq_seg(const float* __restrict__ z,
                       const float* __restrict__ out_idx,
                       const int* __restrict__ sorted,
                       float* __restrict__ dwacc, int NT, int packOK) {
    const int gw   = blockIdx.x * 4 + (threadIdx.x >> 6);
    const int lane = threadIdx.x & 63;
    const int base = gw * 64;
    if (base >= NT) return;
    const int n = (NT - base < 64) ? (NT - base) : 64;

    int tok = 0, code = 0x7fffffff;
    if (lane < n) {
        int e = sorted[base + lane];
        if (packOK) { tok = e & 0x3ffff; code = e >> 18; }
        else        { tok = e; code = (int)out_idx[tok]; }
    }

    int j = 0;
    while (j < n) {
        const int c = __shfl(code, j, 64);
        unsigned long long neq = __ballot(code != c);
        neq &= ~((j == 0) ? 0ULL : ((1ULL << j) - 1ULL));
        int run_end = (neq == 0ULL) ? 64 : (__ffsll((long long)neq) - 1);
        if (run_end > n) run_end = n;

        float acc = 0.f;
        int i = j;
        for (; i + 4 <= run_end; i += 4) {
            int t0 = __shfl(tok, i, 64),     t1 = __shfl(tok, i + 1, 64);
            int t2 = __shfl(tok, i + 2, 64), t3 = __shfl(tok, i + 3, 64);
            float a0 = z[(size_t)t0 * 64 + lane];
            float a1 = z[(size_t)t1 * 64 + lane];
            float a2 = z[(size_t)t2 * 64 + lane];
            float a3 = z[(size_t)t3 * 64 + lane];
            acc += (a0 + a1) + (a2 + a3);
        }
        for (; i < run_end; ++i) {
            int t0 = __shfl(tok, i, 64);
            acc += z[(size_t)t0 * 64 + lane];
        }
        atomicAdd(&dwacc[(size_t)c * 64 + lane], OMD * acc);
        j = run_end;
    }
}

__global__ void vq_final(const float* __restrict__ cs,
                         const float* __restrict__ ema,
                         const float* __restrict__ dwacc,
                         const int* __restrict__ cnt,
                         const float* __restrict__ misc,
                         float* __restrict__ out, int NT, int K) {
    const int KD = K * 64;
    int t = blockIdx.x * 256 + threadIdx.x;
    if (t >= KD) return;
    const int k = t >> 6;
    const float n = misc[1];
    const float dw = DECAY * ema[t] + dwacc[t];
    const float ncs = DECAY * cs[k] + OMD * (float)cnt[k];
    const float csn = (ncs + EPSV) / (n + (float)K * EPSV) * n;
    const size_t off_cb  = (size_t)NT * 64 + NT + 1;
    const size_t off_cs  = off_cb + (size_t)KD;
    const size_t off_ema = off_cs + K;
    out[off_cb  + t] = dw / csn;
    out[off_ema + t] = dw;
    if ((t & 63) == 0) out[off_cs + k] = ncs;
}

extern "C" void kernel_launch(void* const* d_in, const int* in_sizes, int n_in,
                              void* d_out, int out_size, void* d_ws, size_t ws_size,
                              hipStream_t stream) {
    const float* z   = (const float*)d_in[0];
    const float* cb  = (const float*)d_in[1];
    const float* cs  = (const float*)d_in[2];
    const float* ema = (const float*)d_in[3];
    float* out = (float*)d_out;

    const int NT = in_sizes[0] / 64;
    const int K  = in_sizes[2];
    const int KD = K * 64;
    const int Kpad = (K + 15) & ~15;
    const int Ktiles = Kpad / 16;

    // ibits: low key bits holding (tt<<2)|r
    int ibits = 8;
    while ((1 << ibits) < Ktiles * 4) ++ibits;
    const unsigned kmask = ~((1u << ibits) - 1u);
    const int smallK = (K <= 1024);
    const int packOK = (NT <= (1 << 18)) && (K <= (1 << 13));

    auto r4 = [](int x) { return (x + 3) & ~3; };
    int* wsi = (int*)d_ws;
    float* wsf = (float*)d_ws;
    const int o_cnt  = 0;
    const int o_cur  = o_cnt + r4(Kpad);
    const int o_off  = o_cur + r4(K);
    const int o_sort = o_off + r4(K);
    const int o_dw   = o_sort + r4(NT);
    const int o_cbb  = o_dw + KD;              // ushort[Kpad*64] = Kpad*32 dwords
    const int o_cn   = o_cbb + Kpad * 32;
    const int o_misc = o_cn + r4(Kpad);

    int* cnt = wsi + o_cnt;
    int* cur = wsi + o_cur;
    int* off = wsi + o_off;
    int* sorted = wsi + o_sort;
    float* dwacc = wsf + o_dw;
    unsigned short* cbb = (unsigned short*)(wsi + o_cbb);
    float* cnormp = wsf + o_cn;
    float* misc = wsf + o_misc;

    vq_prep<<<(Kpad * 64 + 255) / 256, 256, 0, stream>>>(cb, cbb, cnormp, dwacc, cnt, misc, K, Kpad);
    vq_main<<<(NT + 127) / 128, 256, 0, stream>>>(z, cb, cbb, cnormp, cnt, misc, out,
                                                  NT, K, Ktiles, kmask, smallK);
    vq_scan<<<1, 1024, 0, stream>>>(cs, cnt, cur, off, misc, out, NT, K);
    vq_scatter<<<(NT + 255) / 256, 256, 0, stream>>>(out + (size_t)NT * 64, cur, sorted, NT, packOK);
    vq_seg<<<(NT + 255) / 256, 256, 0, stream>>>(z, out + (size_t)NT * 64, sorted, dwacc, NT, packOK);
    vq_final<<<(KD + 255) / 256, 256, 0, stream>>>(cs, ema, dwacc, cnt, misc, out, NT, K);
}